// Round 6
// baseline (252.108 us; speedup 1.0000x reference)
//
#include <hip/hip_runtime.h>

#define NB   4096
#define NBLK 512
#define NJ   8       // b's per block (NBLK*NJ == NB)

typedef __attribute__((ext_vector_type(4))) float f32x4;
typedef __attribute__((ext_vector_type(8))) short short8;
typedef __attribute__((ext_vector_type(4))) int   int4v;
typedef __attribute__((ext_vector_type(2))) int   int2v;

union Frag { int4v i; short8 s; };

__device__ __forceinline__ unsigned short f2bf(float f) {
  unsigned int u = __float_as_uint(f);
  u = (u + 0x7FFFu + ((u >> 16) & 1u)) >> 16;
  return (unsigned short)u;
}

__device__ __forceinline__ int cvtpk(float lo, float hi) {
  int r;
  asm("v_cvt_pk_bf16_f32 %0, %1, %2" : "=v"(r) : "v"(lo), "v"(hi));
  return r;
}

// ---------------------------------------------------------------------------
// Pre-kernel: conv_w f32 [o=128][i=128][k=2] -> bf16 B-fragments in d_ws.
// Fragment f = ((kk*2 + ker)*8 + ng); lane l holds 8 bf16:
//   col = ng*16 + (l&15),  k = kk*32 + (l>>4)*8 + j (j=0..7)
// at ws + f*1024B + l*16B.   (validated R1-R4)
// ---------------------------------------------------------------------------
__global__ __launch_bounds__(512)
void wconv_kernel(const float* __restrict__ conv_w, unsigned short* __restrict__ ws)
{
  int flat = blockIdx.x * 512 + threadIdx.x;   // 0..4095
  int lane = flat & 63;
  int ng   = (flat >> 6) & 7;
  int ker  = (flat >> 9) & 1;
  int kk   = flat >> 10;
  int col  = ng * 16 + (lane & 15);
  int k0   = kk * 32 + (lane >> 4) * 8;
  short8 s;
#pragma unroll
  for (int j = 0; j < 8; ++j)
    s[j] = (short)f2bf(conv_w[col * 256 + (k0 + j) * 2 + ker]);
  *(short8*)(ws + (size_t)flat * 8) = s;
}

// ---------------------------------------------------------------------------
// Main kernel LDS map (bytes):  total 74816 -> 2 blocks/CU (149.6 KB of 160)
//   A0  bf16 [128 rows][272B]   [0,     34816)
//   A1  bf16 [128 rows][272B]   [34816, 69632)
//   RED f32  [2][128]           [69632, 70656)
//   IDX int  [NJ*128]           [70656, 74752)
//   PTR float* [8]              [74752, 74816)
// ---------------------------------------------------------------------------
#define A0_OFF  0
#define A1_OFF  34816
#define RED_OFF 69632
#define IDX_OFF 70656
#define PTR_OFF 74752
#define LDS_BYTES 74816
#define A_STRIDE 272

__global__ __launch_bounds__(512, 4)
void path_emb_kernel(const int* __restrict__ path_input,
                     const int* __restrict__ path_type,
                     const float* __restrict__ t0, const float* __restrict__ t1,
                     const float* __restrict__ t2, const float* __restrict__ t3,
                     const unsigned short* __restrict__ wfrag,
                     const float* __restrict__ conv_b,
                     float* __restrict__ out)
{
  __shared__ __align__(16) char lds[LDS_BYTES];
  const int blk  = blockIdx.x;
  const int tid  = threadIdx.x;
  const int wid  = tid >> 6;
  const int lane = tid & 63;
  const int lrow = lane & 15;
  const int lk   = lane >> 4;
  const int R = wid & 1;      // row half (64 rows)
  const int C = wid >> 1;     // col quarter (32 cols)

  // ---- prologue: indices + table-pointer LUT into LDS
  if (tid < NJ * 128 / 4)
    ((int4v*)(lds + IDX_OFF))[tid] =
        ((const int4v*)(path_input + (size_t)blk * NJ * 128))[tid];
  if (tid < 8) {
    int ty = path_type[tid];
    const float* tb = (ty == 0) ? t0 : (ty == 1) ? t1 : (ty == 2) ? t2 : t3;
    ((const float**)(lds + PTR_OFF))[tid] = tb;
  }
  float cb = (tid < 128) ? conv_b[tid] : 0.0f;

  // ---- W fragments resident in VGPRs
  Frag wreg[4][2][2];   // [kk][ker][n]
#pragma unroll
  for (int kk = 0; kk < 4; ++kk)
#pragma unroll
    for (int ker = 0; ker < 2; ++ker)
#pragma unroll
      for (int n = 0; n < 2; ++n) {
        int f = (kk * 2 + ker) * 8 + C * 2 + n;
        wreg[kk][ker][n].i = *(const int4v*)(wfrag + (size_t)f * 512 + lane * 8);
      }
  __syncthreads();  // idx/ptr visible

  // Gather: 4 threads per row; instruction i reads 64B-aligned chunk i of the
  // row, lane gq taking 16 consecutive bytes -> 16 coalesced 64B requests/instr.
  const int grow = tid >> 2;
  const int gq   = tid & 3;

  auto ISSUE = [&](int j, f32x4 (&ld)[8]) {
    int idx = ((const int*)(lds + IDX_OFF))[j * 128 + grow];
    const float* tb = ((const float* const*)(lds + PTR_OFF))[grow & 7];
    const float* g  = tb + (size_t)idx * 128 + gq * 4;
#pragma unroll
    for (int i = 0; i < 8; ++i) ld[i] = *(const f32x4*)(g + i * 16);
  };
  // ld[i] = row floats [i*16 + gq*4, +4) -> bf16 at byte i*32 + gq*8
  auto WRITE = [&](int bufoff, const f32x4 (&ld)[8]) {
    char* dst = lds + bufoff + grow * A_STRIDE + gq * 8;
#pragma unroll
    for (int i = 0; i < 8; ++i) {
      int2v w;
      w[0] = cvtpk(ld[i][0], ld[i][1]);
      w[1] = cvtpk(ld[i][2], ld[i][3]);
      *(int2v*)(dst + i * 32) = w;
    }
  };

  float* red = (float*)(lds + RED_OFF);
  const int arow0 = R * 64 + lrow;

  auto COMPUTE = [&](int bufc) {
    f32x4 accA[4][2] = {};
    f32x4 accB[4][2] = {};
    const char* Ab = lds + bufc;
#pragma unroll
    for (int kk = 0; kk < 4; ++kk) {
      Frag a[4];
#pragma unroll
      for (int m = 0; m < 4; ++m)
        a[m].i = *(const int4v*)(Ab + (arow0 + m * 16) * A_STRIDE + kk * 64 + lk * 16);
#pragma unroll
      for (int m = 0; m < 4; ++m)
#pragma unroll
        for (int n = 0; n < 2; ++n) {
          accA[m][n] = __builtin_amdgcn_mfma_f32_16x16x32_bf16(
              a[m].s, wreg[kk][0][n].s, accA[m][n], 0, 0, 0);
          accB[m][n] = __builtin_amdgcn_mfma_f32_16x16x32_bf16(
              a[m].s, wreg[kk][1][n].s, accB[m][n], 0, 0, 0);
        }
    }
    float vmax[2] = {-1e30f, -1e30f};
#pragma unroll
    for (int m = 0; m < 4; ++m)
#pragma unroll
      for (int n = 0; n < 2; ++n) {
        float up = __shfl_down(accB[m][n][0], 16);
#pragma unroll
        for (int r = 0; r < 4; ++r) {
          int rloc = lk * 4 + r;
          if ((rloc & 7) == 7) continue;     // t==7: no window
          float y2 = (r < 3) ? accB[m][n][r + 1] : up;
          vmax[n] = fmaxf(vmax[n], accA[m][n][r] + y2);
        }
      }
#pragma unroll
    for (int n = 0; n < 2; ++n) {
      float v = vmax[n];
      v = fmaxf(v, __shfl_xor(v, 16));
      v = fmaxf(v, __shfl_xor(v, 32));
      vmax[n] = v;
    }
    if (lane < 16) {
#pragma unroll
      for (int n = 0; n < 2; ++n)
        red[R * 128 + C * 32 + n * 16 + lane] = vmax[n];
    }
  };

  // lgkm-only barrier: LDS ordered, global loads/stores stay in flight
  auto BAR = [&]() {
    asm volatile("s_waitcnt lgkmcnt(0)" ::: "memory");
    __builtin_amdgcn_sched_barrier(0);
    __builtin_amdgcn_s_barrier();
    __builtin_amdgcn_sched_barrier(0);
  };

  // ---- depth-1 prefetch pipeline, 2 independent blocks/CU overlap phases
  f32x4 ld[8];
  ISSUE(0, ld);
  WRITE(A0_OFF, ld);
  BAR();

#pragma unroll 1
  for (int j = 0; j < NJ; ++j) {
    const int bufc = (j & 1) ? A1_OFF : A0_OFF;
    const int bufn = (j & 1) ? A0_OFF : A1_OFF;
    const bool pf  = (j + 1 < NJ);

    if (pf) ISSUE(j + 1, ld);          // in flight across GEMM
    __builtin_amdgcn_sched_barrier(0);

    COMPUTE(bufc);                     // acc -> red (LDS)
    BAR();                             // red visible to all waves

    if (pf) WRITE(bufn, ld);           // vmcnt wait happens here

    if (tid < 128)                     // fire-and-forget global store
      out[(size_t)(blk * NJ + j) * 128 + tid] =
          fmaxf(red[tid], red[128 + tid]) + cb;

    BAR();                             // bufn visible; red consumed
  }
}

extern "C" void kernel_launch(void* const* d_in, const int* in_sizes, int n_in,
                              void* d_out, int out_size, void* d_ws, size_t ws_size,
                              hipStream_t stream) {
  const int*   path_input = (const int*)d_in[0];
  const int*   path_type  = (const int*)d_in[3];
  const float* user_emb   = (const float*)d_in[4];
  const float* item_emb   = (const float*)d_in[5];
  const float* ca_emb     = (const float*)d_in[6];
  const float* ci_emb     = (const float*)d_in[7];
  const float* conv_w     = (const float*)d_in[8];
  const float* conv_b     = (const float*)d_in[9];
  float* out = (float*)d_out;
  unsigned short* wfrag = (unsigned short*)d_ws;   // 64 KB bf16 fragment buffer

  wconv_kernel<<<dim3(8), dim3(512), 0, stream>>>(conv_w, wfrag);
  path_emb_kernel<<<dim3(NBLK), dim3(512), 0, stream>>>(
      path_input, path_type, user_emb, item_emb, ca_emb, ci_emb,
      wfrag, conv_b, out);
}

// Round 7
// 52.803 us; speedup vs baseline: 4.7745x; 4.7745x over previous
//
#include <hip/hip_runtime.h>

#define NB   4096
#define NBLK 512
#define NJ   8       // b's per block (NBLK*NJ == NB)

typedef __attribute__((ext_vector_type(4))) float f32x4;
typedef __attribute__((ext_vector_type(8))) short short8;
typedef __attribute__((ext_vector_type(4))) int   int4v;
typedef __attribute__((ext_vector_type(2))) int   int2v;

union Frag { int4v i; short8 s; };

__device__ __forceinline__ unsigned short f2bf(float f) {
  unsigned int u = __float_as_uint(f);
  u = (u + 0x7FFFu + ((u >> 16) & 1u)) >> 16;
  return (unsigned short)u;
}

__device__ __forceinline__ int cvtpk(float lo, float hi) {
  int r;
  asm("v_cvt_pk_bf16_f32 %0, %1, %2" : "=v"(r) : "v"(lo), "v"(hi));
  return r;
}

// ---------------------------------------------------------------------------
// Pre-kernel: conv_w f32 [o=128][i=128][k=2] -> bf16 B-fragments in d_ws.
// Fragment f = ((kk*2 + ker)*8 + ng); lane l holds 8 bf16:
//   col = ng*16 + (l&15),  k = kk*32 + (l>>4)*8 + j (j=0..7)
// at ws + f*1024B + l*16B.   (validated R1-R5)
// ---------------------------------------------------------------------------
__global__ __launch_bounds__(512)
void wconv_kernel(const float* __restrict__ conv_w, unsigned short* __restrict__ ws)
{
  int flat = blockIdx.x * 512 + threadIdx.x;   // 0..4095
  int lane = flat & 63;
  int ng   = (flat >> 6) & 7;
  int ker  = (flat >> 9) & 1;
  int kk   = flat >> 10;
  int col  = ng * 16 + (lane & 15);
  int k0   = kk * 32 + (lane >> 4) * 8;
  short8 s;
#pragma unroll
  for (int j = 0; j < 8; ++j)
    s[j] = (short)f2bf(conv_w[col * 256 + (k0 + j) * 2 + ker]);
  *(short8*)(ws + (size_t)flat * 8) = s;
}

// ---------------------------------------------------------------------------
// Main kernel LDS map (bytes):  total 74816 -> 2 blocks/CU (149.6 KB of 160)
//   A0  bf16 [128 rows][272B]   [0,     34816)
//   A1  bf16 [128 rows][272B]   [34816, 69632)
//   RED f32  [2][128]           [69632, 70656)
//   IDX int  [NJ*128]           [70656, 74752)
//   PTR float* [8]              [74752, 74816)
// Occupancy control is via LDS only; launch_bounds(512,2) keeps the R2-R4
// register allocation (~100-116 VGPR < 128), so 2 blocks/CU are schedulable.
// (R5's (512,4) forced a 64-VGPR budget -> 1 GB/dispatch of scratch spills.)
// ---------------------------------------------------------------------------
#define A0_OFF  0
#define A1_OFF  34816
#define RED_OFF 69632
#define IDX_OFF 70656
#define PTR_OFF 74752
#define LDS_BYTES 74816
#define A_STRIDE 272

__global__ __launch_bounds__(512, 2)
void path_emb_kernel(const int* __restrict__ path_input,
                     const int* __restrict__ path_type,
                     const float* __restrict__ t0, const float* __restrict__ t1,
                     const float* __restrict__ t2, const float* __restrict__ t3,
                     const unsigned short* __restrict__ wfrag,
                     const float* __restrict__ conv_b,
                     float* __restrict__ out)
{
  __shared__ __align__(16) char lds[LDS_BYTES];
  const int blk  = blockIdx.x;
  const int tid  = threadIdx.x;
  const int wid  = tid >> 6;
  const int lane = tid & 63;
  const int lrow = lane & 15;
  const int lk   = lane >> 4;
  const int R = wid & 1;      // row half (64 rows)
  const int C = wid >> 1;     // col quarter (32 cols)

  // ---- prologue: indices + table-pointer LUT into LDS
  if (tid < NJ * 128 / 4)
    ((int4v*)(lds + IDX_OFF))[tid] =
        ((const int4v*)(path_input + (size_t)blk * NJ * 128))[tid];
  if (tid < 8) {
    int ty = path_type[tid];
    const float* tb = (ty == 0) ? t0 : (ty == 1) ? t1 : (ty == 2) ? t2 : t3;
    ((const float**)(lds + PTR_OFF))[tid] = tb;
  }
  float cb = (tid < 128) ? conv_b[tid] : 0.0f;

  // ---- W fragments resident in VGPRs
  Frag wreg[4][2][2];   // [kk][ker][n]
#pragma unroll
  for (int kk = 0; kk < 4; ++kk)
#pragma unroll
    for (int ker = 0; ker < 2; ++ker)
#pragma unroll
      for (int n = 0; n < 2; ++n) {
        int f = (kk * 2 + ker) * 8 + C * 2 + n;
        wreg[kk][ker][n].i = *(const int4v*)(wfrag + (size_t)f * 512 + lane * 8);
      }
  __syncthreads();  // idx/ptr visible

  // Gather: 4 threads per row; instruction i reads 64B-aligned chunk i of the
  // row, lane gq taking 16 consecutive bytes -> 16 coalesced 64B requests/instr.
  const int grow = tid >> 2;
  const int gq   = tid & 3;

  auto ISSUE = [&](int j, f32x4 (&ld)[8]) {
    int idx = ((const int*)(lds + IDX_OFF))[j * 128 + grow];
    const float* tb = ((const float* const*)(lds + PTR_OFF))[grow & 7];
    const float* g  = tb + (size_t)idx * 128 + gq * 4;
#pragma unroll
    for (int i = 0; i < 8; ++i) ld[i] = *(const f32x4*)(g + i * 16);
  };
  // ld[i] = row floats [i*16 + gq*4, +4) -> bf16 at byte i*32 + gq*8
  auto WRITE = [&](int bufoff, const f32x4 (&ld)[8]) {
    char* dst = lds + bufoff + grow * A_STRIDE + gq * 8;
#pragma unroll
    for (int i = 0; i < 8; ++i) {
      int2v w;
      w[0] = cvtpk(ld[i][0], ld[i][1]);
      w[1] = cvtpk(ld[i][2], ld[i][3]);
      *(int2v*)(dst + i * 32) = w;
    }
  };

  float* red = (float*)(lds + RED_OFF);
  const int arow0 = R * 64 + lrow;

  auto COMPUTE = [&](int bufc) {
    f32x4 accA[4][2] = {};
    f32x4 accB[4][2] = {};
    const char* Ab = lds + bufc;
#pragma unroll
    for (int kk = 0; kk < 4; ++kk) {
      Frag a[4];
#pragma unroll
      for (int m = 0; m < 4; ++m)
        a[m].i = *(const int4v*)(Ab + (arow0 + m * 16) * A_STRIDE + kk * 64 + lk * 16);
#pragma unroll
      for (int m = 0; m < 4; ++m)
#pragma unroll
        for (int n = 0; n < 2; ++n) {
          accA[m][n] = __builtin_amdgcn_mfma_f32_16x16x32_bf16(
              a[m].s, wreg[kk][0][n].s, accA[m][n], 0, 0, 0);
          accB[m][n] = __builtin_amdgcn_mfma_f32_16x16x32_bf16(
              a[m].s, wreg[kk][1][n].s, accB[m][n], 0, 0, 0);
        }
    }
    float vmax[2] = {-1e30f, -1e30f};
#pragma unroll
    for (int m = 0; m < 4; ++m)
#pragma unroll
      for (int n = 0; n < 2; ++n) {
        float up = __shfl_down(accB[m][n][0], 16);
#pragma unroll
        for (int r = 0; r < 4; ++r) {
          int rloc = lk * 4 + r;
          if ((rloc & 7) == 7) continue;     // t==7: no window
          float y2 = (r < 3) ? accB[m][n][r + 1] : up;
          vmax[n] = fmaxf(vmax[n], accA[m][n][r] + y2);
        }
      }
#pragma unroll
    for (int n = 0; n < 2; ++n) {
      float v = vmax[n];
      v = fmaxf(v, __shfl_xor(v, 16));
      v = fmaxf(v, __shfl_xor(v, 32));
      vmax[n] = v;
    }
    if (lane < 16) {
#pragma unroll
      for (int n = 0; n < 2; ++n)
        red[R * 128 + C * 32 + n * 16 + lane] = vmax[n];
    }
  };

  // lgkm-only barrier: LDS ordered, global loads/stores stay in flight
  auto BAR = [&]() {
    asm volatile("s_waitcnt lgkmcnt(0)" ::: "memory");
    __builtin_amdgcn_sched_barrier(0);
    __builtin_amdgcn_s_barrier();
    __builtin_amdgcn_sched_barrier(0);
  };

  // ---- depth-1 prefetch pipeline, 2 independent blocks/CU overlap phases
  f32x4 ld[8];
  ISSUE(0, ld);
  WRITE(A0_OFF, ld);
  BAR();

#pragma unroll 1
  for (int j = 0; j < NJ; ++j) {
    const int bufc = (j & 1) ? A1_OFF : A0_OFF;
    const int bufn = (j & 1) ? A0_OFF : A1_OFF;
    const bool pf  = (j + 1 < NJ);

    if (pf) ISSUE(j + 1, ld);          // in flight across GEMM
    __builtin_amdgcn_sched_barrier(0);

    COMPUTE(bufc);                     // acc -> red (LDS)
    BAR();                             // red visible to all waves

    if (pf) WRITE(bufn, ld);           // vmcnt wait happens here

    if (tid < 128)                     // fire-and-forget global store
      out[(size_t)(blk * NJ + j) * 128 + tid] =
          fmaxf(red[tid], red[128 + tid]) + cb;

    BAR();                             // bufn visible; red consumed
  }
}

extern "C" void kernel_launch(void* const* d_in, const int* in_sizes, int n_in,
                              void* d_out, int out_size, void* d_ws, size_t ws_size,
                              hipStream_t stream) {
  const int*   path_input = (const int*)d_in[0];
  const int*   path_type  = (const int*)d_in[3];
  const float* user_emb   = (const float*)d_in[4];
  const float* item_emb   = (const float*)d_in[5];
  const float* ca_emb     = (const float*)d_in[6];
  const float* ci_emb     = (const float*)d_in[7];
  const float* conv_w     = (const float*)d_in[8];
  const float* conv_b     = (const float*)d_in[9];
  float* out = (float*)d_out;
  unsigned short* wfrag = (unsigned short*)d_ws;   // 64 KB bf16 fragment buffer

  wconv_kernel<<<dim3(8), dim3(512), 0, stream>>>(conv_w, wfrag);
  path_emb_kernel<<<dim3(NBLK), dim3(512), 0, stream>>>(
      path_input, path_type, user_emb, item_emb, ca_emb, ci_emb,
      wfrag, conv_b, out);
}